// Round 1
// baseline (98.635 us; speedup 1.0000x reference)
//
#include <hip/hip_runtime.h>
#include <stdint.h>

// Problem constants (from reference): x (8,64,28,28) f32, w (64,64,3,3) f32,
// bias (64) f32, lut (256,256) f32 where lut = outer(arange(-128,128)^2)
// => lut[a+128][b+128] == a*b exactly. So the LUT conv IS an int8 conv.
constexpr int Bn  = 8;
constexpr int Cc  = 64;
constexpr int Hh  = 28;
constexpr int Wd  = 28;
constexpr int NX  = Bn * Cc * Hh * Wd;   // 401408
constexpr int NW  = 64 * 64 * 9;         // 36864
constexpr int HW  = Hh * Wd;             // 784
constexpr int CHW = Cc * HW;             // 50176

// ws layout:
//   float partial[96]   (block absmax partials: 0..63 -> x, 64..95 -> w)
//   float scalars[3]    (s_x, s_w, s_x*s_w) at partial+96
//   byte 512:           qw int8, layout (co,kh,kw,ci), 36864 B
//   byte 37376:         qx int8, layout (b,h,w,ci) NHWC, 401408 B
// total 438784 B

__device__ __forceinline__ int8_t q8(float v, float s) {
  float q = rintf(v / s);                      // round-half-even == jnp.round
  q = fminf(fmaxf(q, -128.0f), 127.0f);
  return (int8_t)(int)q;
}

__global__ __launch_bounds__(256) void k_max(const float* __restrict__ x,
                                             const float* __restrict__ w,
                                             float* __restrict__ partial) {
  int bid = blockIdx.x, tid = threadIdx.x;
  const float* src; int n, nb, b0;
  if (bid < 64) { src = x; n = NX; nb = 64; b0 = bid; }
  else          { src = w; n = NW; nb = 32; b0 = bid - 64; }
  float m = 0.0f;
  for (int i = b0 * 256 + tid; i < n; i += nb * 256)
    m = fmaxf(m, fabsf(src[i]));
  for (int off = 32; off > 0; off >>= 1)
    m = fmaxf(m, __shfl_down(m, off));        // wave64 reduce
  __shared__ float sm[4];
  if ((tid & 63) == 0) sm[tid >> 6] = m;
  __syncthreads();
  if (tid == 0) partial[bid] = fmaxf(fmaxf(sm[0], sm[1]), fmaxf(sm[2], sm[3]));
}

// One kernel quantizes both tensors. Each thread handles 4 consecutive ci
// (one char4 store). X quads: 100352 (grid part 0), W quads: 9216.
__global__ __launch_bounds__(256) void k_quant(const float* __restrict__ x,
                                               const float* __restrict__ w,
                                               const float* __restrict__ partial,
                                               float* __restrict__ scalars,
                                               char* __restrict__ qx,
                                               char* __restrict__ qw) {
  __shared__ float s_sx, s_sw;
  if (threadIdx.x == 0) {
    float mx = 0.0f, mw = 0.0f;
    for (int i = 0; i < 64; ++i)  mx = fmaxf(mx, partial[i]);
    for (int i = 64; i < 96; ++i) mw = fmaxf(mw, partial[i]);
    // match JAX fp32 weak-type math: EMA*T as double -> f32, (1-EMA) -> f32
    float Tf = (float)(0.95 * 3.0) + (float)(1.0 - 0.95) * mx;
    float Tw = (float)(0.95 * 0.3) + (float)(1.0 - 0.95) * mw;
    s_sx = Tf / 127.0f;
    s_sw = Tw / 127.0f;
    if (blockIdx.x == 0) {
      scalars[0] = s_sx; scalars[1] = s_sw; scalars[2] = s_sx * s_sw;
    }
  }
  __syncthreads();
  int t = blockIdx.x * 256 + threadIdx.x;
  if (t < 100352) {
    // x: src NCHW -> dest NHWC. quad q: ci4 = q&15, hw = (q>>4)%784, b = q/12544
    int q = t;
    int ci4 = q & 15;
    int hw  = (q >> 4) % HW;
    int b   = q / (16 * HW);
    const float* ps = x + b * CHW + (ci4 * 4) * HW + hw;  // stride HW over c
    float s = s_sx;
    char4 r;
    r.x = q8(ps[0 * HW], s);
    r.y = q8(ps[1 * HW], s);
    r.z = q8(ps[2 * HW], s);
    r.w = q8(ps[3 * HW], s);
    ((char4*)qx)[q] = r;
  } else {
    // w: src (co,ci,kh,kw) -> dest (co,kh,kw,ci). quad u: ci4=u&15,
    // kw=(u>>4)%3, kh=(u/48)%3, co=u/144
    int u = t - 100352;  // [0, 9216)
    int ci4 = u & 15;
    int kw  = (u >> 4) % 3;
    int kh  = (u / 48) % 3;
    int co  = u / 144;
    const float* ps = w + co * 576 + (ci4 * 4) * 9 + kh * 3 + kw;  // stride 9 over ci
    float s = s_sw;
    char4 r;
    r.x = q8(ps[0 * 9], s);
    r.y = q8(ps[1 * 9], s);
    r.z = q8(ps[2 * 9], s);
    r.w = q8(ps[3 * 9], s);
    ((char4*)qw)[u] = r;
  }
}

// Direct conv: one thread per output element (NCHW), int32 accumulate.
// acc <= 576*128*128 = 9.4M, exact. Padding contributes q(0)=0, matching ref.
__global__ __launch_bounds__(256) void k_conv(const char* __restrict__ qx,
                                              const char* __restrict__ qw,
                                              const float* __restrict__ scalars,
                                              const float* __restrict__ bias,
                                              float* __restrict__ out) {
  int t = blockIdx.x * 256 + threadIdx.x;   // 401408 exact
  int ow = t % Wd;
  int oh = (t / Wd) % Hh;
  int co = (t / HW) % Cc;
  int b  = t / CHW;
  int acc = 0;
  const int* pw_base = (const int*)(qw + co * 576);
  #pragma unroll
  for (int kh = 0; kh < 3; ++kh) {
    int ih = oh + kh - 1;
    if (ih < 0 || ih >= Hh) continue;
    #pragma unroll
    for (int kw = 0; kw < 3; ++kw) {
      int iw = ow + kw - 1;
      if (iw < 0 || iw >= Wd) continue;
      const int* px = (const int*)(qx + (b * HW + ih * Wd + iw) * 64);
      const int* pw = pw_base + (kh * 3 + kw) * 16;
      #pragma unroll
      for (int i = 0; i < 16; ++i) {
        int a = px[i], bb = pw[i];
        acc += (int)(int8_t)(a)        * (int)(int8_t)(bb)
             + (int)(int8_t)(a >> 8)   * (int)(int8_t)(bb >> 8)
             + (int)(int8_t)(a >> 16)  * (int)(int8_t)(bb >> 16)
             + (a >> 24)               * (bb >> 24);
      }
    }
  }
  out[t] = (float)acc * scalars[2] + bias[co];
}

extern "C" void kernel_launch(void* const* d_in, const int* in_sizes, int n_in,
                              void* d_out, int out_size, void* d_ws, size_t ws_size,
                              hipStream_t stream) {
  const float* x    = (const float*)d_in[0];
  const float* w    = (const float*)d_in[1];
  const float* bias = (const float*)d_in[2];
  // d_in[3] (lut) unused: lut[a+128][b+128] == a*b exactly for this input.
  float* out = (float*)d_out;

  char*  wsb     = (char*)d_ws;
  float* partial = (float*)wsb;          // 96 floats
  float* scalars = partial + 96;         // 3 floats (byte 384..395)
  char*  qw      = wsb + 512;            // 36864 B
  char*  qx      = wsb + 512 + NW;       // 401408 B at byte 37376

  k_max<<<96, 256, 0, stream>>>(x, w, partial);
  k_quant<<<428, 256, 0, stream>>>(x, w, partial, scalars, qx, qw);
  k_conv<<<NX / 256, 256, 0, stream>>>(qx, qw, scalars, bias, out);
}

// Round 2
// 83.000 us; speedup vs baseline: 1.1884x; 1.1884x over previous
//
#include <hip/hip_runtime.h>
#include <stdint.h>

// lut = outer(arange(-128,128), same) => lut[a+128][b+128] == a*b exactly,
// so the LUT conv IS an int8 conv; int32 accum is exact (<= 9.4M < 2^31).
constexpr int Bn  = 8;
constexpr int Cc  = 64;
constexpr int Hh  = 28;
constexpr int Wd  = 28;
constexpr int NX  = Bn * Cc * Hh * Wd;   // 401408
constexpr int NW  = 64 * 64 * 9;         // 36864
constexpr int HW  = Hh * Wd;             // 784
constexpr int CHW = Cc * HW;             // 50176

#if __has_builtin(__builtin_amdgcn_sdot4)
__device__ __forceinline__ int dot4(int a, int b, int c) {
  return __builtin_amdgcn_sdot4(a, b, c, false);
}
#else
__device__ __forceinline__ int dot4(int a, int b, int c) {
  return c + (int)(int8_t)(a)       * (int)(int8_t)(b)
           + (int)(int8_t)(a >> 8)  * (int)(int8_t)(b >> 8)
           + (int)(int8_t)(a >> 16) * (int)(int8_t)(b >> 16)
           + (a >> 24)              * (b >> 24);
}
#endif

__device__ __forceinline__ int q8i(float v, float s) {
  float q = rintf(v / s);                  // round-half-even == jnp.round
  q = fminf(fmaxf(q, -128.0f), 127.0f);
  return (int)q;
}

// ws: float partial[96]; float scalars[3] at +96; qw int8 (co,kh,kw,ci) at byte 512.

__global__ __launch_bounds__(256) void k_max(const float* __restrict__ x,
                                             const float* __restrict__ w,
                                             float* __restrict__ partial) {
  int bid = blockIdx.x, tid = threadIdx.x;
  const float4* src; int n4, nb, b0;
  if (bid < 64) { src = (const float4*)x; n4 = NX / 4; nb = 64; b0 = bid; }
  else          { src = (const float4*)w; n4 = NW / 4; nb = 32; b0 = bid - 64; }
  float m = 0.0f;
  for (int i = b0 * 256 + tid; i < n4; i += nb * 256) {
    float4 v = src[i];
    m = fmaxf(m, fmaxf(fmaxf(fabsf(v.x), fabsf(v.y)), fmaxf(fabsf(v.z), fabsf(v.w))));
  }
  for (int off = 32; off > 0; off >>= 1)
    m = fmaxf(m, __shfl_down(m, off));
  __shared__ float sm[4];
  if ((tid & 63) == 0) sm[tid >> 6] = m;
  __syncthreads();
  if (tid == 0) partial[bid] = fmaxf(fmaxf(sm[0], sm[1]), fmaxf(sm[2], sm[3]));
}

// Quantize w (co,ci,kh,kw) -> qw (co,kh,kw,ci) int8, and publish scalars.
__global__ __launch_bounds__(256) void k_quantw(const float* __restrict__ w,
                                                const float* __restrict__ partial,
                                                float* __restrict__ scalars,
                                                char* __restrict__ qw) {
  __shared__ float s_sw;
  if (threadIdx.x == 0) {
    float mx = 0.0f, mw = 0.0f;
    for (int i = 0; i < 64; ++i)  mx = fmaxf(mx, partial[i]);
    for (int i = 64; i < 96; ++i) mw = fmaxf(mw, partial[i]);
    float Tf = (float)(0.95 * 3.0) + (float)(1.0 - 0.95) * mx;
    float Tw = (float)(0.95 * 0.3) + (float)(1.0 - 0.95) * mw;
    float sx = Tf / 127.0f, sw = Tw / 127.0f;
    s_sw = sw;
    if (blockIdx.x == 0) { scalars[0] = sx; scalars[1] = sw; scalars[2] = sx * sw; }
  }
  __syncthreads();
  int u = blockIdx.x * 256 + threadIdx.x;   // 9216 char4 quads
  if (u >= NW / 4) return;
  int ci4 = u & 15;
  int kw  = (u >> 4) % 3;
  int kh  = (u / 48) % 3;
  int co  = u / 144;
  const float* ps = w + co * 576 + (ci4 * 4) * 9 + kh * 3 + kw;  // stride 9 over ci
  float s = s_sw;
  int v = (q8i(ps[0], s) & 255)
        | ((q8i(ps[9], s) & 255) << 8)
        | ((q8i(ps[18], s) & 255) << 16)
        | ((q8i(ps[27], s) & 255) << 24);
  ((int*)qw)[u] = v;
}

// One block per (b, oh). Quantize the 3 needed x-rows into LDS (transposed
// [ci4][row][iw_slot] dwords, conflict-free b32 reads), stage all qw in LDS,
// dot4 over ci. Thread t: ow = t&31 (28 active), co group g = t>>5 (8 co each).
__global__ __launch_bounds__(256) void k_conv(const float* __restrict__ x,
                                              const char* __restrict__ qw,
                                              const float* __restrict__ scalars,
                                              const float* __restrict__ bias,
                                              float* __restrict__ out) {
  __shared__ int swd[9216];        // qw dwords: [co][tap(9)][ci4(16)]
  __shared__ int sx[16 * 96];      // [ci4][row(3)][slot(32)]; slot = iw+1

  int bx = blockIdx.x;
  int oh = bx % 28;
  int b  = bx / 28;
  int t  = threadIdx.x;
  float s_x  = scalars[0];
  float s_xw = scalars[2];

  // stage w: 2304 int4 = 9 per thread, coalesced
  const int4* gw = (const int4*)qw;
  #pragma unroll
  for (int i = 0; i < 9; ++i) {
    int j = t + i * 256;
    ((int4*)swd)[j] = gw[j];
  }

  // stage x: 1344 dwords (3 rows x 16 ci4 x 28 iw); zero if ih out of range
  for (int j = t; j < 1344; j += 256) {
    int r   = j / 448;
    int j2  = j - r * 448;
    int ci4 = j2 / 28;
    int iw  = j2 - ci4 * 28;
    int ih  = oh + r - 1;
    int v = 0;
    if (ih >= 0 && ih < Hh) {
      const float* ps = x + b * CHW + (ci4 * 4) * HW + ih * Wd + iw;
      v = (q8i(ps[0 * HW], s_x) & 255)
        | ((q8i(ps[1 * HW], s_x) & 255) << 8)
        | ((q8i(ps[2 * HW], s_x) & 255) << 16)
        | ((q8i(ps[3 * HW], s_x) & 255) << 24);
    }
    sx[ci4 * 96 + r * 32 + (iw + 1)] = v;
  }
  // zero pad slots {0,29,30,31} for each (ci4, r): 192 dwords
  if (t < 192) {
    int ci4 = t / 12;
    int rs  = t - ci4 * 12;
    int r   = rs >> 2;
    int s   = rs & 3;
    int slot = (s == 0) ? 0 : (28 + s);
    sx[ci4 * 96 + r * 32 + slot] = 0;
  }
  __syncthreads();

  int ow = t & 31;
  int g  = t >> 5;           // co = g*8 + coi
  int ow_r = (ow < 28) ? ow : 27;  // keep junk lanes in-bounds

  int acc[8];
  #pragma unroll
  for (int i = 0; i < 8; ++i) acc[i] = 0;

  const int4* w4p = (const int4*)swd;
  #pragma unroll
  for (int r = 0; r < 3; ++r) {
    #pragma unroll
    for (int kw = 0; kw < 3; ++kw) {
      int tap  = r * 3 + kw;
      int slot = ow_r + kw;
      #pragma unroll
      for (int c16 = 0; c16 < 4; ++c16) {
        int x0 = sx[(c16 * 4 + 0) * 96 + r * 32 + slot];
        int x1 = sx[(c16 * 4 + 1) * 96 + r * 32 + slot];
        int x2 = sx[(c16 * 4 + 2) * 96 + r * 32 + slot];
        int x3 = sx[(c16 * 4 + 3) * 96 + r * 32 + slot];
        #pragma unroll
        for (int coi = 0; coi < 8; ++coi) {
          int4 wv = w4p[(g * 8 + coi) * 36 + tap * 4 + c16];
          int a = acc[coi];
          a = dot4(x0, wv.x, a);
          a = dot4(x1, wv.y, a);
          a = dot4(x2, wv.z, a);
          a = dot4(x3, wv.w, a);
          acc[coi] = a;
        }
      }
    }
  }

  if (ow < 28) {
    #pragma unroll
    for (int coi = 0; coi < 8; ++coi) {
      int co = g * 8 + coi;
      out[b * CHW + co * HW + oh * Wd + ow] = (float)acc[coi] * s_xw + bias[co];
    }
  }
}

extern "C" void kernel_launch(void* const* d_in, const int* in_sizes, int n_in,
                              void* d_out, int out_size, void* d_ws, size_t ws_size,
                              hipStream_t stream) {
  const float* x    = (const float*)d_in[0];
  const float* w    = (const float*)d_in[1];
  const float* bias = (const float*)d_in[2];
  // d_in[3] (lut) unused: lut[a+128][b+128] == a*b exactly.
  float* out = (float*)d_out;

  char*  wsb     = (char*)d_ws;
  float* partial = (float*)wsb;          // 96 floats
  float* scalars = partial + 96;         // 3 floats
  char*  qw      = wsb + 512;            // 36864 B

  k_max<<<96, 256, 0, stream>>>(x, w, partial);
  k_quantw<<<36, 256, 0, stream>>>(w, partial, scalars, qw);
  k_conv<<<Bn * Hh, 256, 0, stream>>>(x, qw, scalars, bias, out);
}